// Round 7
// baseline (97.155 us; speedup 1.0000x reference)
//
#include <hip/hip_runtime.h>

// Sinkhorn on 8192 independent 64x64 f32 matrices, FOUR waves per matrix.
// x stays diag(u)*K*diag(v). Wave q (0..3) holds:
//   rK[k] = A[lane][16q+k]  (row `lane`, 16-col slice)  -> partial K*v
//   cK[i] = A[16q+i][lane]  (col `lane`, 16-row slice)  -> partial K^T*u
// u/v stored ROTATED (lane l holds index (l+16q)&63) so all readlane
// indices are literals 0..15.
// Exchange buffers are TRANSPOSED [4][64]: write xb[q][lane] (bank=lane%32,
// conflict-free) and read xb[j][c] as scalar reads from one per-lane base
// (c bijective in lane -> conflict-free; compiler merges to ds_read2_b32).
// R6's [64][4] layout was an 8-way bank conflict on both sides (8.06M cyc).

static constexpr int   kIters = 20;
static constexpr float kEps   = 1e-6f;

__device__ __forceinline__ float RLf(float x, int l) {
    return __int_as_float(__builtin_amdgcn_readlane(__float_as_int(x), l));
}

__global__ __launch_bounds__(256) void sinkhorn64_q4t(const float* __restrict__ in,
                                                      float* __restrict__ out) {
    __shared__ float xbW[4][64];   // K*v   partials [wave][row]
    __shared__ float xbT[4][64];   // K^T*u partials [wave][col]
    __shared__ float vbuf[64];     // final v unrotate
    const int tid  = threadIdx.x;
    const int q    = tid >> 6;                 // wave's quarter (0..3)
    const int lane = tid & 63;
    const int c    = (lane + 16 * q) & 63;     // rotated index for this lane
    const long m   = blockIdx.x;               // matrix 0..8191
    const float* __restrict__ A = in  + m * 4096;
    float* __restrict__ O       = out + m * 4096;

    // cK[i] = A[16q+i][lane]  (16 coalesced 256B loads)
    float cK[16];
#pragma unroll
    for (int i = 0; i < 16; ++i) cK[i] = A[((16 * q + i) << 6) + lane];

    // rK[k] = A[lane][16q+k]  (4 x float4; lines hot in L1/L2 from cK pass)
    float rK[16];
#pragma unroll
    for (int k4 = 0; k4 < 4; ++k4) {
        const float4 f = *reinterpret_cast<const float4*>(A + (lane << 6) + 16 * q + (k4 << 2));
        rK[4 * k4 + 0] = f.x; rK[4 * k4 + 1] = f.y;
        rK[4 * k4 + 2] = f.z; rK[4 * k4 + 3] = f.w;
    }

    // Row-max: 16-term partial, 4-way exchange, combine plain (for rK)
    // and rotated (for cK via literal readlane).
    float pm = rK[0];
#pragma unroll
    for (int k = 1; k < 16; ++k) pm = fmaxf(pm, rK[k]);
    xbT[q][lane] = pm;
    __syncthreads();
    const float mx  = fmaxf(fmaxf(xbT[0][lane], xbT[1][lane]),
                            fmaxf(xbT[2][lane], xbT[3][lane]));   // row `lane`
    const float mxc = fmaxf(fmaxf(xbT[0][c], xbT[1][c]),
                            fmaxf(xbT[2][c], xbT[3][c]));         // row `c`

#pragma unroll
    for (int k = 0; k < 16; ++k) rK[k] = __expf(rK[k] - mx);
#pragma unroll
    for (int i = 0; i < 16; ++i) cK[i] = __expf(cK[i] - RLf(mxc, i)); // mx_{16q+i}

    // Rotated scaling vectors: lane holds u_c, v_c.
    float u = 1.0f, v = 1.0f;

#pragma unroll 1
    for (int it = 0; it < kIters; ++it) {
        // ---- partial (K v)_{row=lane} over own 16 columns ----
        float a0 = 0.f, a1 = 0.f, a2 = 0.f, a3 = 0.f;
#pragma unroll
        for (int k = 0; k < 16; k += 4) {
            a0 = fmaf(RLf(v, k + 0), rK[k + 0], a0);   // v_{16q+k} at lane k
            a1 = fmaf(RLf(v, k + 1), rK[k + 1], a1);
            a2 = fmaf(RLf(v, k + 2), rK[k + 2], a2);
            a3 = fmaf(RLf(v, k + 3), rK[k + 3], a3);
        }
        xbW[q][lane] = (a0 + a1) + (a2 + a3);
        __syncthreads();
        const float w = (xbW[0][c] + xbW[1][c]) + (xbW[2][c] + xbW[3][c]);
        u = u * __builtin_amdgcn_rcpf(fmaf(u, w, kEps));

        // ---- partial (K^T u)_{col=lane} over own 16 rows ----
        float b0 = 0.f, b1 = 0.f, b2 = 0.f, b3 = 0.f;
#pragma unroll
        for (int i = 0; i < 16; i += 4) {
            b0 = fmaf(RLf(u, i + 0), cK[i + 0], b0);   // u_{16q+i} at lane i
            b1 = fmaf(RLf(u, i + 1), cK[i + 1], b1);
            b2 = fmaf(RLf(u, i + 2), cK[i + 2], b2);
            b3 = fmaf(RLf(u, i + 3), cK[i + 3], b3);
        }
        xbT[q][lane] = (b0 + b1) + (b2 + b3);
        __syncthreads();
        const float t = (xbT[0][c] + xbT[1][c]) + (xbT[2][c] + xbT[3][c]);
        v = v * __builtin_amdgcn_rcpf(fmaf(v, t, kEps));
    }

    // Unrotate v: vbuf[c] = v_c, then read plain layout.
    vbuf[c] = v;
    __syncthreads();
    const float vf = vbuf[lane];

    // O[16q+i][lane] = u_{16q+i} * K[16q+i][lane] * v_lane  (coalesced)
#pragma unroll
    for (int i = 0; i < 16; ++i) {
        O[((16 * q + i) << 6) + lane] = RLf(u, i) * cK[i] * vf;
    }
}

extern "C" void kernel_launch(void* const* d_in, const int* in_sizes, int n_in,
                              void* d_out, int out_size, void* d_ws, size_t ws_size,
                              hipStream_t stream) {
    const float* in = (const float*)d_in[0];
    float* out      = (float*)d_out;
    // One matrix per 256-thread (4-wave) block.
    sinkhorn64_q4t<<<8192, 256, 0, stream>>>(in, out);
}

// Round 8
// 89.585 us; speedup vs baseline: 1.0845x; 1.0845x over previous
//
#include <hip/hip_runtime.h>

// Sinkhorn on 8192 independent 64x64 f32 matrices, TWO waves per matrix
// (R4 structure — best instruction economy), with __launch_bounds__(128,2)
// to raise the VGPR budget (cap 256) so rK[32]+cK[32] stay register-resident
// instead of being re-loaded from cache inside the 20-iteration loop
// (R4's VGPR_Count=52 < 64 live floats proved re-materialization).
// Wave h (h=0,1) holds:
//   rK[k] = A[lane][32h+k]   (row `lane`, its column-half)  -> partial K*v
//   cK[i] = A[32h+i][lane]   (col `lane`, its row-half)     -> partial K^T*u
// u/v stored ROTATED (lane l holds index (l+32h)&63) so readlane indices
// are literals 0..31. Per matvec: 32 RL + 32 FMA, one 2-wave LDS exchange,
// one barrier.

static constexpr int   kIters = 20;
static constexpr float kEps   = 1e-6f;

__device__ __forceinline__ float RLf(float x, int l) {
    return __int_as_float(__builtin_amdgcn_readlane(__float_as_int(x), l));
}

__global__ __launch_bounds__(128, 2) void sinkhorn64_lb(const float* __restrict__ in,
                                                        float* __restrict__ out) {
    __shared__ float xb0[2][64];   // exchange buffer 0  [half][lane]
    __shared__ float xb1[2][64];   // exchange buffer 1
    const int tid  = threadIdx.x;
    const int h    = tid >> 6;               // which half this wave owns
    const int lane = tid & 63;
    const int c    = (lane + 32 * h) & 63;   // rotated index (self-inverse)
    const long m   = blockIdx.x;             // matrix 0..8191
    const float* __restrict__ A = in  + m * 4096;
    float* __restrict__ O       = out + m * 4096;

    // cK[i] = A[32h+i][lane]  (32 coalesced 256B loads)
    float cK[32];
#pragma unroll
    for (int i = 0; i < 32; ++i) cK[i] = A[((32 * h + i) << 6) + lane];

    // rK[k] = A[lane][32h+k]  (8 x float4 per lane; lines hot from cK pass)
    float rK[32];
#pragma unroll
    for (int k4 = 0; k4 < 8; ++k4) {
        const float4 f = *reinterpret_cast<const float4*>(A + (lane << 6) + 32 * h + (k4 << 2));
        rK[4 * k4 + 0] = f.x; rK[4 * k4 + 1] = f.y;
        rK[4 * k4 + 2] = f.z; rK[4 * k4 + 3] = f.w;
    }

    // Row max: own-half partial, exchange, combine (both plain and rotated).
    float pm = rK[0];
#pragma unroll
    for (int k = 1; k < 32; ++k) pm = fmaxf(pm, rK[k]);
    xb0[h][lane] = pm;
    __syncthreads();
    const float mx  = fmaxf(pm, xb0[1 - h][lane]);   // max of row `lane`
    const float mxr = fmaxf(xb0[0][c], xb0[1][c]);   // max of row `c`

#pragma unroll
    for (int k = 0; k < 32; ++k) rK[k] = __expf(rK[k] - mx);
#pragma unroll
    for (int i = 0; i < 32; ++i) cK[i] = __expf(cK[i] - RLf(mxr, i));

    // Rotated scaling vectors: lane holds u_c, v_c (identical full vectors
    // in both waves, each rotated by 32h so needed values sit at lanes 0..31).
    float ur = 1.0f, vr = 1.0f;

#pragma unroll 1
    for (int it = 0; it < kIters; ++it) {
        // partial (K v)_{row=lane} over own columns; v[32h+k] = lane k of vr
        float a0 = 0.f, a1 = 0.f, a2 = 0.f, a3 = 0.f;
#pragma unroll
        for (int k = 0; k < 32; k += 4) {
            a0 = fmaf(RLf(vr, k + 0), rK[k + 0], a0);
            a1 = fmaf(RLf(vr, k + 1), rK[k + 1], a1);
            a2 = fmaf(RLf(vr, k + 2), rK[k + 2], a2);
            a3 = fmaf(RLf(vr, k + 3), rK[k + 3], a3);
        }
        xb1[h][lane] = (a0 + a1) + (a2 + a3);
        __syncthreads();
        const float w = xb1[0][c] + xb1[1][c];            // w for row c
        ur = ur * __builtin_amdgcn_rcpf(fmaf(ur, w, kEps));

        // partial (K^T u)_{col=lane} over own rows; u[32h+i] = lane i of ur
        float b0 = 0.f, b1 = 0.f, b2 = 0.f, b3 = 0.f;
#pragma unroll
        for (int i = 0; i < 32; i += 4) {
            b0 = fmaf(RLf(ur, i + 0), cK[i + 0], b0);
            b1 = fmaf(RLf(ur, i + 1), cK[i + 1], b1);
            b2 = fmaf(RLf(ur, i + 2), cK[i + 2], b2);
            b3 = fmaf(RLf(ur, i + 3), cK[i + 3], b3);
        }
        xb0[h][lane] = (b0 + b1) + (b2 + b3);
        __syncthreads();
        const float t = xb0[0][c] + xb0[1][c];            // t for col c
        vr = vr * __builtin_amdgcn_rcpf(fmaf(vr, t, kEps));
    }

    // Unrotate v: wave0's vr is already identity layout.
    xb1[h][lane] = vr;
    __syncthreads();
    const float vfin = xb1[0][lane];

    // O[32h+i][lane] = u_{32h+i} * K[32h+i][lane] * v_lane  (coalesced)
#pragma unroll
    for (int i = 0; i < 32; ++i) {
        O[((32 * h + i) << 6) + lane] = RLf(ur, i) * cK[i] * vfin;
    }
}

extern "C" void kernel_launch(void* const* d_in, const int* in_sizes, int n_in,
                              void* d_out, int out_size, void* d_ws, size_t ws_size,
                              hipStream_t stream) {
    const float* in = (const float*)d_in[0];
    float* out      = (float*)d_out;
    // One matrix per 128-thread (2-wave) block.
    sinkhorn64_lb<<<8192, 128, 0, stream>>>(in, out);
}